// Round 1
// baseline (9602.966 us; speedup 1.0000x reference)
//
#include <hip/hip_runtime.h>

#define Bq 16
#define Cc 128
#define Tt 4096
#define Qq 8
#define Kk 1024
#define Nn (Bq*Tt)   // 65536 rows

// ws layout: [0..7] double closs accumulator; [64 ..) float ee[Q*K]

__global__ __launch_bounds__(256) void ee_kernel(const float* __restrict__ emb,
                                                 float* __restrict__ ee,
                                                 double* __restrict__ closs) {
    int i = blockIdx.x * 256 + threadIdx.x;
    if (i == 0) *closs = 0.0;
    if (i < Qq * Kk) {
        const float* e = emb + (size_t)i * Cc;
        float s0 = 0.f, s1 = 0.f, s2 = 0.f, s3 = 0.f;
#pragma unroll
        for (int c = 0; c < Cc; c += 4) {
            s0 = fmaf(e[c],     e[c],     s0);
            s1 = fmaf(e[c + 1], e[c + 1], s1);
            s2 = fmaf(e[c + 2], e[c + 2], s2);
            s3 = fmaf(e[c + 3], e[c + 3], s3);
        }
        ee[i] = (s0 + s1) + (s2 + s3);
    }
}

// Block = 256 threads = 4 waves. Each block owns 64 rows (lane -> row).
// All 4 waves hold the same 64 rows; wave w scans codes [w*256, w*256+256).
// Per stage: per-wave argmin -> LDS combine (first-min tie-break) -> all waves
// gather winning code row and update their residual copy identically.
__global__ __launch_bounds__(256, 3) void vq_kernel(
    const float* __restrict__ latents,
    const float* __restrict__ emb,
    const float* __restrict__ ee,
    float* __restrict__ quantized,
    float* __restrict__ codes,
    double* __restrict__ closs)
{
    const int lane = threadIdx.x & 63;
    const int wv   = threadIdx.x >> 6;
    const int n    = blockIdx.x * 64 + lane;
    const int bb   = n >> 12;          // T = 4096
    const int tt   = n & (Tt - 1);
    const float* lat = latents + (size_t)bb * Cc * Tt + tt;

    float r[Cc];
#pragma unroll
    for (int c = 0; c < Cc; ++c) r[c] = lat[(size_t)c * Tt];

    float rr;
    {
        float s0 = 0.f, s1 = 0.f, s2 = 0.f, s3 = 0.f;
#pragma unroll
        for (int c = 0; c < Cc; c += 4) {
            s0 = fmaf(r[c],     r[c],     s0);
            s1 = fmaf(r[c + 1], r[c + 1], s1);
            s2 = fmaf(r[c + 2], r[c + 2], s2);
            s3 = fmaf(r[c + 3], r[c + 3], s3);
        }
        rr = (s0 + s1) + (s2 + s3);
    }

    __shared__ float s_sc[4][64];
    __shared__ int   s_ix[4][64];

    double closs_d = 0.0;

    for (int q = 0; q < Qq; ++q) {
        const float* eq  = emb + (size_t)q * Kk * Cc;
        const float* eeq = ee + q * Kk;

        float best  = 3.4e38f;
        int   bestk = 0;
        const int kbase = wv * 256;
        for (int k = kbase; k < kbase + 256; ++k) {
            const float* ek = eq + (size_t)k * Cc;   // wave-uniform -> s_load
            float a0 = 0.f, a1 = 0.f, a2 = 0.f, a3 = 0.f;
#pragma unroll
            for (int c = 0; c < Cc; c += 4) {
                a0 = fmaf(r[c],     ek[c],     a0);
                a1 = fmaf(r[c + 1], ek[c + 1], a1);
                a2 = fmaf(r[c + 2], ek[c + 2], a2);
                a3 = fmaf(r[c + 3], ek[c + 3], a3);
            }
            float dot = (a0 + a1) + (a2 + a3);
            float d = (rr - 2.0f * dot) + eeq[k];    // reference association
            if (d < best) { best = d; bestk = k; }
        }

        s_sc[wv][lane] = best;
        s_ix[wv][lane] = bestk;
        __syncthreads();
        float gb = s_sc[0][lane];
        int   gi = s_ix[0][lane];
#pragma unroll
        for (int j = 1; j < 4; ++j) {
            float sj = s_sc[j][lane];
            int   ij = s_ix[j][lane];
            if (sj < gb) { gb = sj; gi = ij; }       // strict <: first-occurrence
        }
        __syncthreads();

        if (wv == 0) codes[((size_t)bb * Qq + q) * Tt + tt] = (float)gi;

        // gather winner row, update residual, recompute rr (= this stage's closs term)
        const float* ew = eq + (size_t)gi * Cc;
        float s0 = 0.f, s1 = 0.f, s2 = 0.f, s3 = 0.f;
#pragma unroll
        for (int c = 0; c < Cc; c += 4) {
            float q0 = ew[c], q1 = ew[c + 1], q2 = ew[c + 2], q3 = ew[c + 3];
            r[c]     -= q0; r[c + 1] -= q1; r[c + 2] -= q2; r[c + 3] -= q3;
            s0 = fmaf(r[c],     r[c],     s0);
            s1 = fmaf(r[c + 1], r[c + 1], s1);
            s2 = fmaf(r[c + 2], r[c + 2], s2);
            s3 = fmaf(r[c + 3], r[c + 3], s3);
        }
        rr = (s0 + s1) + (s2 + s3);
        closs_d += (double)rr;
    }

    if (wv == 0) {
        // quantized = latents - residual_final
#pragma unroll
        for (int c = 0; c < Cc; ++c) {
            float lv = lat[(size_t)c * Tt];
            quantized[((size_t)bb * Cc + c) * Tt + tt] = lv - r[c];
        }
        // closs: one contribution per row (waves 1..3 are replicas)
        for (int off = 32; off; off >>= 1) closs_d += __shfl_down(closs_d, off);
        if (lane == 0) atomicAdd(closs, closs_d);
    }
}

__global__ void fin_kernel(const double* __restrict__ closs, float* __restrict__ loss_out) {
    loss_out[0] = (float)(*closs / (double)((size_t)Nn * Cc * Qq));
    loss_out[1] = 0.0f;
}

extern "C" void kernel_launch(void* const* d_in, const int* in_sizes, int n_in,
                              void* d_out, int out_size, void* d_ws, size_t ws_size,
                              hipStream_t stream) {
    const float* latents = (const float*)d_in[0];
    const float* emb     = (const float*)d_in[1];
    float* out       = (float*)d_out;
    float* quantized = out;                                   // B*C*T
    float* codes     = out + (size_t)Bq * Cc * Tt;            // B*Q*T
    float* loss      = codes + (size_t)Bq * Qq * Tt;          // 2 scalars
    double* closs    = (double*)d_ws;
    float*  ee       = (float*)((char*)d_ws + 64);

    ee_kernel<<<(Qq * Kk + 255) / 256, 256, 0, stream>>>(emb, ee, closs);
    vq_kernel<<<Nn / 64, 256, 0, stream>>>(latents, emb, ee, quantized, codes, closs);
    fin_kernel<<<1, 1, 0, stream>>>(closs, loss);
}

// Round 4
// 4917.495 us; speedup vs baseline: 1.9528x; 1.9528x over previous
//
#include <hip/hip_runtime.h>

#define Bq 16
#define Cc 128
#define Tt 4096
#define Qq 8
#define Kk 1024
#define Nn (Bq*Tt)   // 65536 rows

// ws layout: [0..7] double closs accumulator; [64 ..) float ee[Q*K]

__global__ __launch_bounds__(256) void ee_kernel(const float* __restrict__ emb,
                                                 float* __restrict__ ee,
                                                 double* __restrict__ closs) {
    int i = blockIdx.x * 256 + threadIdx.x;
    if (i == 0) *closs = 0.0;
    if (i < Qq * Kk) {
        const float* e = emb + (size_t)i * Cc;
        float s0 = 0.f, s1 = 0.f, s2 = 0.f, s3 = 0.f;
#pragma unroll
        for (int c = 0; c < Cc; c += 4) {
            s0 = fmaf(e[c],     e[c],     s0);
            s1 = fmaf(e[c + 1], e[c + 1], s1);
            s2 = fmaf(e[c + 2], e[c + 2], s2);
            s3 = fmaf(e[c + 3], e[c + 3], s3);
        }
        ee[i] = (s0 + s1) + (s2 + s3);
    }
}

// Block = 256 threads = 4 waves. Each block owns 64 rows (lane -> row).
// All 4 waves hold the same 64 rows in registers; wave w scans codes
// [w*256, w*256+256) with a wave-UNIFORM (readfirstlane) base so the
// embedding stream compiles to s_load (scalar pipe), keeping all VGPRs
// for the residual row r[128].
__global__ __launch_bounds__(256, 2) void vq_kernel(
    const float* __restrict__ latents,
    const float* __restrict__ emb,
    const float* __restrict__ ee,
    float* __restrict__ quantized,
    float* __restrict__ codes,
    double* __restrict__ closs)
{
    const int lane = threadIdx.x & 63;
    const int wv   = threadIdx.x >> 6;
    // wave-uniform scalar copy of the wave id -> SGPR
    const int wvu  = __builtin_amdgcn_readfirstlane(wv);

    const int n  = blockIdx.x * 64 + lane;
    const int bb = n >> 12;          // T = 4096
    const int tt = n & (Tt - 1);
    const float* lat = latents + (size_t)bb * Cc * Tt + tt;

    float r[Cc];
#pragma unroll
    for (int c = 0; c < Cc; ++c) r[c] = lat[(size_t)c * Tt];

    float rr;
    {
        float s0 = 0.f, s1 = 0.f, s2 = 0.f, s3 = 0.f;
#pragma unroll
        for (int c = 0; c < Cc; c += 4) {
            s0 = fmaf(r[c],     r[c],     s0);
            s1 = fmaf(r[c + 1], r[c + 1], s1);
            s2 = fmaf(r[c + 2], r[c + 2], s2);
            s3 = fmaf(r[c + 3], r[c + 3], s3);
        }
        rr = (s0 + s1) + (s2 + s3);
    }

    __shared__ float s_sc[4][64];
    __shared__ int   s_ix[4][64];

    double closs_d = 0.0;

    for (int q = 0; q < Qq; ++q) {
        const float* eq = emb + (size_t)q * Kk * Cc;
        // uniform bases -> scalar loads
        const float* ekb = eq + (size_t)wvu * 256 * Cc;
        const float* eeb = ee + q * Kk + wvu * 256;

        float best  = 3.4e38f;
        int   bestk = 0;
#pragma unroll 1
        for (int k = 0; k < 256; ++k) {
            const float* ek = ekb + (size_t)k * Cc;   // uniform -> s_load
            float a0 = 0.f, a1 = 0.f, a2 = 0.f, a3 = 0.f;
#pragma unroll
            for (int c = 0; c < Cc; c += 4) {
                a0 = fmaf(r[c],     ek[c],     a0);
                a1 = fmaf(r[c + 1], ek[c + 1], a1);
                a2 = fmaf(r[c + 2], ek[c + 2], a2);
                a3 = fmaf(r[c + 3], ek[c + 3], a3);
            }
            float dot = (a0 + a1) + (a2 + a3);
            float d = (rr - 2.0f * dot) + eeb[k];     // reference association
            bool lt = d < best;                       // strict <: first-occurrence
            best  = lt ? d : best;
            bestk = lt ? (wvu * 256 + k) : bestk;
        }

        s_sc[wv][lane] = best;
        s_ix[wv][lane] = bestk;
        __syncthreads();
        float gb = s_sc[0][lane];
        int   gi = s_ix[0][lane];
#pragma unroll
        for (int j = 1; j < 4; ++j) {
            float sj = s_sc[j][lane];
            int   ij = s_ix[j][lane];
            if (sj < gb) { gb = sj; gi = ij; }        // ascending wave: first-min
        }
        __syncthreads();

        if (wv == 0) codes[((size_t)bb * Qq + q) * Tt + tt] = (float)gi;

        // gather winner row, update residual, recompute rr (= stage closs term)
        const float* ew = eq + (size_t)gi * Cc;
        float s0 = 0.f, s1 = 0.f, s2 = 0.f, s3 = 0.f;
#pragma unroll
        for (int c = 0; c < Cc; c += 4) {
            float q0 = ew[c], q1 = ew[c + 1], q2 = ew[c + 2], q3 = ew[c + 3];
            r[c]     -= q0; r[c + 1] -= q1; r[c + 2] -= q2; r[c + 3] -= q3;
            s0 = fmaf(r[c],     r[c],     s0);
            s1 = fmaf(r[c + 1], r[c + 1], s1);
            s2 = fmaf(r[c + 2], r[c + 2], s2);
            s3 = fmaf(r[c + 3], r[c + 3], s3);
        }
        rr = (s0 + s1) + (s2 + s3);
        closs_d += (double)rr;
    }

    // quantized = latents - residual_final; waves split channels (all waves
    // hold identical r after identical updates)
#pragma unroll
    for (int c0 = 0; c0 < 32; ++c0) {
        int c = wv * 32 + c0;
        float lv = lat[(size_t)c * Tt];
        quantized[((size_t)bb * Cc + c) * Tt + tt] = lv - r[c];
    }

    if (wv == 0) {
        // closs: one contribution per row (waves 1..3 are replicas)
        for (int off = 32; off; off >>= 1) closs_d += __shfl_down(closs_d, off);
        if (lane == 0) atomicAdd(closs, closs_d);
    }
}

__global__ void fin_kernel(const double* __restrict__ closs, float* __restrict__ loss_out) {
    loss_out[0] = (float)(*closs / (double)((size_t)Nn * Cc * Qq));
    loss_out[1] = 0.0f;
}

extern "C" void kernel_launch(void* const* d_in, const int* in_sizes, int n_in,
                              void* d_out, int out_size, void* d_ws, size_t ws_size,
                              hipStream_t stream) {
    const float* latents = (const float*)d_in[0];
    const float* emb     = (const float*)d_in[1];
    float* out       = (float*)d_out;
    float* quantized = out;                                   // B*C*T
    float* codes     = out + (size_t)Bq * Cc * Tt;            // B*Q*T
    float* loss      = codes + (size_t)Bq * Qq * Tt;          // 2 scalars
    double* closs    = (double*)d_ws;
    float*  ee       = (float*)((char*)d_ws + 64);

    ee_kernel<<<(Qq * Kk + 255) / 256, 256, 0, stream>>>(emb, ee, closs);
    vq_kernel<<<Nn / 64, 256, 0, stream>>>(latents, emb, ee, quantized, codes, closs);
    fin_kernel<<<1, 1, 0, stream>>>(closs, loss);
}

// Round 8
// 4662.458 us; speedup vs baseline: 2.0596x; 1.0547x over previous
//
#include <hip/hip_runtime.h>

#define Bq 16
#define Cc 128
#define Tt 4096
#define Qq 8
#define Kk 1024
#define Nn (Bq*Tt)   // 65536 rows

typedef float f32x32 __attribute__((ext_vector_type(32)));

// ws layout: [0..7] double closs accumulator; [64 ..) float ee[Q*K]

__global__ __launch_bounds__(256) void ee_kernel(const float* __restrict__ emb,
                                                 float* __restrict__ ee,
                                                 double* __restrict__ closs) {
    int i = blockIdx.x * 256 + threadIdx.x;
    if (i == 0) *closs = 0.0;
    if (i < Qq * Kk) {
        const float* e = emb + (size_t)i * Cc;
        float s0 = 0.f, s1 = 0.f, s2 = 0.f, s3 = 0.f;
#pragma unroll
        for (int c = 0; c < Cc; c += 4) {
            s0 = fmaf(e[c],     e[c],     s0);
            s1 = fmaf(e[c + 1], e[c + 1], s1);
            s2 = fmaf(e[c + 2], e[c + 2], s2);
            s3 = fmaf(e[c + 3], e[c + 3], s3);
        }
        ee[i] = (s0 + s1) + (s2 + s3);
    }
}

// Residual row held in four ext_vector(32) floats -> guaranteed VGPR
// residency (every subscript is compile-time constant). Embedding stream is
// wave-uniform (readfirstlane base) -> s_load on the scalar pipe.
__global__ __launch_bounds__(256, 2) void vq_kernel(
    const float* __restrict__ latents,
    const float* __restrict__ emb,
    const float* __restrict__ ee,
    float* __restrict__ quantized,
    float* __restrict__ codes,
    double* __restrict__ closs)
{
    const int lane = threadIdx.x & 63;
    const int wv   = threadIdx.x >> 6;
    const int wvu  = __builtin_amdgcn_readfirstlane(wv);   // SGPR copy

    const int n  = blockIdx.x * 64 + lane;
    const int bb = n >> 12;          // T = 4096
    const int tt = n & (Tt - 1);
    const float* lat = latents + (size_t)bb * Cc * Tt + tt;

    f32x32 rA, rB, rC, rD;
#pragma unroll
    for (int c = 0; c < 32; ++c) {
        rA[c] = lat[(size_t)(c      ) * Tt];
        rB[c] = lat[(size_t)(c + 32 ) * Tt];
        rC[c] = lat[(size_t)(c + 64 ) * Tt];
        rD[c] = lat[(size_t)(c + 96 ) * Tt];
    }

    float rr;
    {
        float s0 = 0.f, s1 = 0.f, s2 = 0.f, s3 = 0.f;
#pragma unroll
        for (int c = 0; c < 32; ++c) {
            s0 = fmaf(rA[c], rA[c], s0);
            s1 = fmaf(rB[c], rB[c], s1);
            s2 = fmaf(rC[c], rC[c], s2);
            s3 = fmaf(rD[c], rD[c], s3);
        }
        rr = (s0 + s1) + (s2 + s3);
    }

    __shared__ float s_sc[4][64];
    __shared__ int   s_ix[4][64];

    double closs_d = 0.0;

    for (int q = 0; q < Qq; ++q) {
        const float* eq  = emb + (size_t)q * Kk * Cc;
        const float* ekb = eq + (size_t)wvu * 256 * Cc;   // uniform -> s_load
        const float* eeb = ee + q * Kk + wvu * 256;

        float best  = 3.4e38f;
        int   bestk = 0;
#pragma unroll 2
        for (int k = 0; k < 256; ++k) {
            const float* ek = ekb + (size_t)k * Cc;
            float a0 = 0.f, a1 = 0.f, a2 = 0.f, a3 = 0.f;
#pragma unroll
            for (int c = 0; c < 8; ++c) {
                a0 = fmaf(rA[4*c  ], ek[4*c  ], a0);
                a1 = fmaf(rA[4*c+1], ek[4*c+1], a1);
                a2 = fmaf(rA[4*c+2], ek[4*c+2], a2);
                a3 = fmaf(rA[4*c+3], ek[4*c+3], a3);
            }
#pragma unroll
            for (int c = 0; c < 8; ++c) {
                a0 = fmaf(rB[4*c  ], ek[32+4*c  ], a0);
                a1 = fmaf(rB[4*c+1], ek[32+4*c+1], a1);
                a2 = fmaf(rB[4*c+2], ek[32+4*c+2], a2);
                a3 = fmaf(rB[4*c+3], ek[32+4*c+3], a3);
            }
#pragma unroll
            for (int c = 0; c < 8; ++c) {
                a0 = fmaf(rC[4*c  ], ek[64+4*c  ], a0);
                a1 = fmaf(rC[4*c+1], ek[64+4*c+1], a1);
                a2 = fmaf(rC[4*c+2], ek[64+4*c+2], a2);
                a3 = fmaf(rC[4*c+3], ek[64+4*c+3], a3);
            }
#pragma unroll
            for (int c = 0; c < 8; ++c) {
                a0 = fmaf(rD[4*c  ], ek[96+4*c  ], a0);
                a1 = fmaf(rD[4*c+1], ek[96+4*c+1], a1);
                a2 = fmaf(rD[4*c+2], ek[96+4*c+2], a2);
                a3 = fmaf(rD[4*c+3], ek[96+4*c+3], a3);
            }
            float dot = (a0 + a1) + (a2 + a3);
            float d = (rr - 2.0f * dot) + eeb[k];     // reference association
            bool lt = d < best;                       // strict <: first-occurrence
            best  = lt ? d : best;
            bestk = lt ? (wvu * 256 + k) : bestk;
        }

        s_sc[wv][lane] = best;
        s_ix[wv][lane] = bestk;
        __syncthreads();
        float gb = s_sc[0][lane];
        int   gi = s_ix[0][lane];
#pragma unroll
        for (int j = 1; j < 4; ++j) {
            float sj = s_sc[j][lane];
            int   ij = s_ix[j][lane];
            if (sj < gb) { gb = sj; gi = ij; }        // ascending wave: first-min
        }
        __syncthreads();

        if (wv == 0) codes[((size_t)bb * Qq + q) * Tt + tt] = (float)gi;

        // per-lane gather of winner row; update residual; recompute rr
        const float4* ew4 = (const float4*)(eq + (size_t)gi * Cc);
        float s0 = 0.f, s1 = 0.f, s2 = 0.f, s3 = 0.f;
#pragma unroll
        for (int j = 0; j < 8; ++j) {
            float4 w = ew4[j];
            rA[4*j  ] -= w.x; rA[4*j+1] -= w.y; rA[4*j+2] -= w.z; rA[4*j+3] -= w.w;
            s0 = fmaf(rA[4*j  ], rA[4*j  ], s0);
            s1 = fmaf(rA[4*j+1], rA[4*j+1], s1);
            s2 = fmaf(rA[4*j+2], rA[4*j+2], s2);
            s3 = fmaf(rA[4*j+3], rA[4*j+3], s3);
        }
#pragma unroll
        for (int j = 0; j < 8; ++j) {
            float4 w = ew4[8 + j];
            rB[4*j  ] -= w.x; rB[4*j+1] -= w.y; rB[4*j+2] -= w.z; rB[4*j+3] -= w.w;
            s0 = fmaf(rB[4*j  ], rB[4*j  ], s0);
            s1 = fmaf(rB[4*j+1], rB[4*j+1], s1);
            s2 = fmaf(rB[4*j+2], rB[4*j+2], s2);
            s3 = fmaf(rB[4*j+3], rB[4*j+3], s3);
        }
#pragma unroll
        for (int j = 0; j < 8; ++j) {
            float4 w = ew4[16 + j];
            rC[4*j  ] -= w.x; rC[4*j+1] -= w.y; rC[4*j+2] -= w.z; rC[4*j+3] -= w.w;
            s0 = fmaf(rC[4*j  ], rC[4*j  ], s0);
            s1 = fmaf(rC[4*j+1], rC[4*j+1], s1);
            s2 = fmaf(rC[4*j+2], rC[4*j+2], s2);
            s3 = fmaf(rC[4*j+3], rC[4*j+3], s3);
        }
#pragma unroll
        for (int j = 0; j < 8; ++j) {
            float4 w = ew4[24 + j];
            rD[4*j  ] -= w.x; rD[4*j+1] -= w.y; rD[4*j+2] -= w.z; rD[4*j+3] -= w.w;
            s0 = fmaf(rD[4*j  ], rD[4*j  ], s0);
            s1 = fmaf(rD[4*j+1], rD[4*j+1], s1);
            s2 = fmaf(rD[4*j+2], rD[4*j+2], s2);
            s3 = fmaf(rD[4*j+3], rD[4*j+3], s3);
        }
        rr = (s0 + s1) + (s2 + s3);
        closs_d += (double)rr;
    }

    // quantized = latents - residual_final; wave w writes channel chunk w
    // (static vector subscripts inside each constant-wv branch)
    {
        float* qrow = quantized + (size_t)bb * Cc * Tt + tt;
        if (wv == 0) {
#pragma unroll
            for (int c = 0; c < 32; ++c)
                qrow[(size_t)(c      ) * Tt] = lat[(size_t)(c      ) * Tt] - rA[c];
        } else if (wv == 1) {
#pragma unroll
            for (int c = 0; c < 32; ++c)
                qrow[(size_t)(c + 32 ) * Tt] = lat[(size_t)(c + 32 ) * Tt] - rB[c];
        } else if (wv == 2) {
#pragma unroll
            for (int c = 0; c < 32; ++c)
                qrow[(size_t)(c + 64 ) * Tt] = lat[(size_t)(c + 64 ) * Tt] - rC[c];
        } else {
#pragma unroll
            for (int c = 0; c < 32; ++c)
                qrow[(size_t)(c + 96 ) * Tt] = lat[(size_t)(c + 96 ) * Tt] - rD[c];
        }
    }

    if (wv == 0) {
        // closs: one contribution per row (waves 1..3 are replicas)
        for (int off = 32; off; off >>= 1) closs_d += __shfl_down(closs_d, off);
        if (lane == 0) atomicAdd(closs, closs_d);
    }
}

__global__ void fin_kernel(const double* __restrict__ closs, float* __restrict__ loss_out) {
    loss_out[0] = (float)(*closs / (double)((size_t)Nn * Cc * Qq));
    loss_out[1] = 0.0f;
}

extern "C" void kernel_launch(void* const* d_in, const int* in_sizes, int n_in,
                              void* d_out, int out_size, void* d_ws, size_t ws_size,
                              hipStream_t stream) {
    const float* latents = (const float*)d_in[0];
    const float* emb     = (const float*)d_in[1];
    float* out       = (float*)d_out;
    float* quantized = out;                                   // B*C*T
    float* codes     = out + (size_t)Bq * Cc * Tt;            // B*Q*T
    float* loss      = codes + (size_t)Bq * Qq * Tt;          // 2 scalars
    double* closs    = (double*)d_ws;
    float*  ee       = (float*)((char*)d_ws + 64);

    ee_kernel<<<(Qq * Kk + 255) / 256, 256, 0, stream>>>(emb, ee, closs);
    vq_kernel<<<Nn / 64, 256, 0, stream>>>(latents, emb, ee, quantized, codes, closs);
    fin_kernel<<<1, 1, 0, stream>>>(closs, loss);
}

// Round 10
// 1806.532 us; speedup vs baseline: 5.3157x; 2.5809x over previous
//
#include <hip/hip_runtime.h>

#define Bq 16
#define Cc 128
#define Tt 4096
#define Qq 8
#define Kk 1024
#define Nn (Bq*Tt)   // 65536 rows

#define ROWS 128     // rows per block
#define NTC  256     // codes per N-tile
#define KCH  32      // k-chunk staged in LDS
#define NTILES (Kk/NTC)    // 4
#define KCHUNKS (Cc/KCH)   // 4

typedef float f32x4 __attribute__((ext_vector_type(4)));
typedef float f32x8 __attribute__((ext_vector_type(8)));
typedef int   i32x8 __attribute__((ext_vector_type(8)));

static __device__ __forceinline__ f32x8 splat8(float x) {
    f32x8 v = {x, x, x, x, x, x, x, x};
    return v;
}

// ws layout: [0..7] double closs; [64..) float ee[Q*K]
__global__ __launch_bounds__(256) void ee_kernel(const float* __restrict__ emb,
                                                 float* __restrict__ ee,
                                                 double* __restrict__ closs) {
    int i = blockIdx.x * 256 + threadIdx.x;
    if (i == 0) *closs = 0.0;
    if (i < Qq * Kk) {
        const float* e = emb + (size_t)i * Cc;
        float s0 = 0.f, s1 = 0.f, s2 = 0.f, s3 = 0.f;
#pragma unroll
        for (int c = 0; c < Cc; c += 4) {
            s0 = fmaf(e[c],     e[c],     s0);
            s1 = fmaf(e[c + 1], e[c + 1], s1);
            s2 = fmaf(e[c + 2], e[c + 2], s2);
            s3 = fmaf(e[c + 3], e[c + 3], s3);
        }
        ee[i] = (s0 + s1) + (s2 + s3);
    }
}

// Fused residual-VQ: one 512-thread block owns 128 rows for all 8 stages.
// Residual r kept persistently in LDS, k-major ([k][row]) so GEMM A-reads
// are conflict-free. Scoring = register-blocked GEMM (8x8 tiles), codes
// staged per (N-tile, k-chunk) into LDS with a transpose-scatter. Argmin
// first-min semantics preserved exactly: in-thread ascending-k strict <,
// cross-lane (d,k)-lexicographic shfl_xor reduce.
__global__ __launch_bounds__(512, 2) void vq_kernel(
    const float* __restrict__ latents,
    const float* __restrict__ emb,
    const float* __restrict__ ee,
    float* __restrict__ quantized,
    float* __restrict__ codes,
    double* __restrict__ closs)
{
    extern __shared__ float smem[];
    float* r_lds  = smem;                        // [128][128] 64KB  (k-major)
    float* B_lds  = smem + Cc * ROWS;            // [32][256]  32KB  (kk-major)
    float* rrp    = B_lds + KCH * NTC;           // [4][128]
    float* rr_lds = rrp + 4 * ROWS;              // [128]
    int*   win    = (int*)(rr_lds + ROWS);       // [128]

    const int t   = threadIdx.x;
    const int tx  = t & 31;     // code-group (8 codes)
    const int ty  = t >> 5;     // row-group  (8 rows)
    const int un  = t & 127;    // row for init/update phases
    const int ukg = t >> 7;     // k-quarter for init/update phases

    const int rowbase = blockIdx.x * ROWS;
    const int bb  = rowbase >> 12;        // 128 | 4096, so one batch per block
    const int tt0 = rowbase & (Tt - 1);

    // ---- init: r = latents (transposed into [k][row]), rr = ||r||^2 ----
    {
        const float* lb = latents + (size_t)bb * Cc * Tt + tt0 + un;
        float part = 0.f;
#pragma unroll
        for (int j = 0; j < KCH; ++j) {
            int k = ukg * KCH + j;
            float v = lb[(size_t)k * Tt];
            r_lds[k * ROWS + un] = v;
            part = fmaf(v, v, part);
        }
        rrp[ukg * ROWS + un] = part;
    }
    __syncthreads();
    if (t < ROWS)
        rr_lds[t] = (rrp[t] + rrp[ROWS + t]) + (rrp[2 * ROWS + t] + rrp[3 * ROWS + t]);
    __syncthreads();

    for (int q = 0; q < Qq; ++q) {
        const float* eq = emb + (size_t)q * Kk * Cc;

        f32x8 best_ = splat8(3.4e38f);
        i32x8 bk_   = {0, 0, 0, 0, 0, 0, 0, 0};
        f32x8 rr8   = *(const f32x8*)&rr_lds[ty * 8];

        for (int nt = 0; nt < NTILES; ++nt) {
            f32x8 acc0 = splat8(0.f), acc1 = splat8(0.f), acc2 = splat8(0.f), acc3 = splat8(0.f);
            f32x8 acc4 = splat8(0.f), acc5 = splat8(0.f), acc6 = splat8(0.f), acc7 = splat8(0.f);

            for (int kc = 0; kc < KCHUNKS; ++kc) {
                __syncthreads();   // previous B reads complete
                // stage B chunk: codes [nt*256,+256) x k [kc*32,+32), transposed
                {
                    const int cl = t >> 1;
                    const int hk = (t & 1) * 16;
                    const float* src = eq + (size_t)(nt * NTC + cl) * Cc + kc * KCH + hk;
#pragma unroll
                    for (int j = 0; j < 4; ++j) {
                        f32x4 v = *(const f32x4*)(src + j * 4);
#pragma unroll
                        for (int i2 = 0; i2 < 4; ++i2)
                            B_lds[(hk + j * 4 + i2) * NTC + cl] = v[i2];
                    }
                }
                __syncthreads();

#pragma unroll 8
                for (int kk = 0; kk < KCH; ++kk) {
                    f32x8 a_ = *(const f32x8*)&r_lds[(kc * KCH + kk) * ROWS + ty * 8];
                    f32x8 b_ = *(const f32x8*)&B_lds[kk * NTC + tx * 8];
                    acc0 = __builtin_elementwise_fma(splat8(a_[0]), b_, acc0);
                    acc1 = __builtin_elementwise_fma(splat8(a_[1]), b_, acc1);
                    acc2 = __builtin_elementwise_fma(splat8(a_[2]), b_, acc2);
                    acc3 = __builtin_elementwise_fma(splat8(a_[3]), b_, acc3);
                    acc4 = __builtin_elementwise_fma(splat8(a_[4]), b_, acc4);
                    acc5 = __builtin_elementwise_fma(splat8(a_[5]), b_, acc5);
                    acc6 = __builtin_elementwise_fma(splat8(a_[6]), b_, acc6);
                    acc7 = __builtin_elementwise_fma(splat8(a_[7]), b_, acc7);
                }
            }

            // fold tile into running best: d = (rr - 2*dot) + ee  (ref association)
            f32x8 ee_ = *(const f32x8*)(ee + q * Kk + nt * NTC + tx * 8);
            const int kbase = nt * NTC + tx * 8;
#define FOLD_ROW(I_) {                                                        \
            f32x8 dv = __builtin_elementwise_fma(splat8(-2.0f), acc##I_,      \
                                                 splat8(rr8[I_])) + ee_;      \
            _Pragma("unroll")                                                 \
            for (int c = 0; c < 8; ++c) {                                     \
                float d = dv[c];                                              \
                bool lt = d < best_[I_];                                      \
                best_[I_] = lt ? d : best_[I_];                               \
                bk_[I_]   = lt ? (kbase + c) : bk_[I_];                       \
            } }
            FOLD_ROW(0) FOLD_ROW(1) FOLD_ROW(2) FOLD_ROW(3)
            FOLD_ROW(4) FOLD_ROW(5) FOLD_ROW(6) FOLD_ROW(7)
#undef FOLD_ROW
        } // nt

        // cross-tx reduce (32 lanes share each row-group); (d,k) lexicographic
#pragma unroll
        for (int m = 1; m < 32; m <<= 1) {
#pragma unroll
            for (int i = 0; i < 8; ++i) {
                float od = __shfl_xor(best_[i], m);
                int   ok = __shfl_xor(bk_[i], m);
                bool rep = (od < best_[i]) || (od == best_[i] && ok < bk_[i]);
                best_[i] = rep ? od : best_[i];
                bk_[i]   = rep ? ok : bk_[i];
            }
        }
        if (tx == 0) {
#pragma unroll
            for (int i = 0; i < 8; ++i) {
                int row = ty * 8 + i;
                win[row] = bk_[i];
                codes[((size_t)bb * Qq + q) * Tt + tt0 + row] = (float)bk_[i];
            }
        }
        __syncthreads();

        // update: r -= e[win]; recompute rr
        {
            const float* er = eq + (size_t)win[un] * Cc + ukg * KCH;
            float part = 0.f;
#pragma unroll
            for (int j = 0; j < 8; ++j) {
                f32x4 ev = *(const f32x4*)(er + j * 4);
#pragma unroll
                for (int i2 = 0; i2 < 4; ++i2) {
                    int k = ukg * KCH + j * 4 + i2;
                    float rv = r_lds[k * ROWS + un] - ev[i2];
                    r_lds[k * ROWS + un] = rv;
                    part = fmaf(rv, rv, part);
                }
            }
            rrp[ukg * ROWS + un] = part;
        }
        __syncthreads();
        if (t < ROWS)
            rr_lds[t] = (rrp[t] + rrp[ROWS + t]) + (rrp[2 * ROWS + t] + rrp[3 * ROWS + t]);
        __syncthreads();
        // closs: sum of new rr over the block's rows
        if (t < 64) {
            double s = (double)rr_lds[t] + (double)rr_lds[t + 64];
#pragma unroll
            for (int off = 32; off; off >>= 1)
                s += __shfl_down(s, off);
            if (t == 0) atomicAdd(closs, s);
        }
    } // q

    // epilogue: quantized = latents - r_final
    {
        const float* lb = latents + (size_t)bb * Cc * Tt + tt0 + un;
        float* qb = quantized + (size_t)bb * Cc * Tt + tt0 + un;
#pragma unroll
        for (int j = 0; j < KCH; ++j) {
            int k = ukg * KCH + j;
            qb[(size_t)k * Tt] = lb[(size_t)k * Tt] - r_lds[k * ROWS + un];
        }
    }
}

__global__ void fin_kernel(const double* __restrict__ closs, float* __restrict__ loss_out) {
    loss_out[0] = (float)(*closs / (double)((size_t)Nn * Cc * Qq));
    loss_out[1] = 0.0f;
}

extern "C" void kernel_launch(void* const* d_in, const int* in_sizes, int n_in,
                              void* d_out, int out_size, void* d_ws, size_t ws_size,
                              hipStream_t stream) {
    const float* latents = (const float*)d_in[0];
    const float* emb     = (const float*)d_in[1];
    float* out       = (float*)d_out;
    float* quantized = out;                                   // B*C*T
    float* codes     = out + (size_t)Bq * Cc * Tt;            // B*Q*T
    float* loss      = codes + (size_t)Bq * Qq * Tt;          // 2 scalars
    double* closs    = (double*)d_ws;
    float*  ee       = (float*)((char*)d_ws + 64);

    const size_t smem = (size_t)(Cc * ROWS + KCH * NTC + 4 * ROWS + ROWS) * sizeof(float)
                      + ROWS * sizeof(int);   // 101376 B
    (void)hipFuncSetAttribute((const void*)vq_kernel,
                              hipFuncAttributeMaxDynamicSharedMemorySize, (int)smem);

    ee_kernel<<<(Qq * Kk + 255) / 256, 256, 0, stream>>>(emb, ee, closs);
    vq_kernel<<<Nn / ROWS, 512, smem, stream>>>(latents, emb, ee, quantized, codes, closs);
    fin_kernel<<<1, 1, 0, stream>>>(closs, loss);
}

// Round 14
// 1759.029 us; speedup vs baseline: 5.4592x; 1.0270x over previous
//
#include <hip/hip_runtime.h>

#define Bq 16
#define Cc 128
#define Tt 4096
#define Qq 8
#define Kk 1024
#define Nn (Bq*Tt)   // 65536 rows

#define ROWS 128     // rows per block
#define NTC  256     // codes per N-tile
#define KCH  32      // k-chunk staged in LDS
#define NTILES (Kk/NTC)    // 4
#define KCHUNKS (Cc/KCH)   // 4
#define NCHUNK (NTILES*KCHUNKS)  // 16

typedef float f32x4 __attribute__((ext_vector_type(4)));
typedef float f32x8 __attribute__((ext_vector_type(8)));
typedef int   i32x8 __attribute__((ext_vector_type(8)));

static __device__ __forceinline__ f32x8 splat8(float x) {
    f32x8 v = {x, x, x, x, x, x, x, x};
    return v;
}

// ws layout: [0..7] double closs; [64..) float ee[Q*K]
__global__ __launch_bounds__(256) void ee_kernel(const float* __restrict__ emb,
                                                 float* __restrict__ ee,
                                                 double* __restrict__ closs) {
    int i = blockIdx.x * 256 + threadIdx.x;
    if (i == 0) *closs = 0.0;
    if (i < Qq * Kk) {
        const float* e = emb + (size_t)i * Cc;
        float s0 = 0.f, s1 = 0.f, s2 = 0.f, s3 = 0.f;
#pragma unroll
        for (int c = 0; c < Cc; c += 4) {
            s0 = fmaf(e[c],     e[c],     s0);
            s1 = fmaf(e[c + 1], e[c + 1], s1);
            s2 = fmaf(e[c + 2], e[c + 2], s2);
            s3 = fmaf(e[c + 3], e[c + 3], s3);
        }
        ee[i] = (s0 + s1) + (s2 + s3);
    }
}

// Fused residual-VQ, GEMM-tiled. One 512-thread block owns 128 rows for all
// 8 stages; residual r persistent in LDS (k-major, broadcast A-reads).
// B (codes) double-buffered in LDS, staged with an async split (issue global
// loads -> compute 32-k chunk -> ds_write -> barrier): one barrier per chunk,
// global latency hidden under FMAs. Per-thread code tile = two float4 groups
// (tx*4, 128+tx*4) so B ds_read_b128 has 16B lane stride -> conflict-free.
__global__ __launch_bounds__(512, 2) void vq_kernel(
    const float* __restrict__ latents,
    const float* __restrict__ emb,
    const float* __restrict__ ee,
    float* __restrict__ quantized,
    float* __restrict__ codes,
    double* __restrict__ closs)
{
    extern __shared__ float smem[];
    float* r_lds  = smem;                        // [128][128] 64KB (k-major)
    float* B_lds  = smem + Cc * ROWS;            // [2][32][256] 64KB
    float* rrp    = B_lds + 2 * KCH * NTC;       // [4][128]
    float* rr_lds = rrp + 4 * ROWS;              // [128]
    int*   win    = (int*)(rr_lds + ROWS);       // [128]

    const int t   = threadIdx.x;
    const int tx  = t & 31;     // code-group
    const int ty  = t >> 5;     // row-group (8 rows)
    const int un  = t & 127;    // row for init/update phases
    const int ukg = t >> 7;     // k-quarter for init/update phases
    const int cl  = t >> 1;     // staging: code
    const int hk  = (t & 1) * 16;  // staging: k-half of chunk

    const int rowbase = blockIdx.x * ROWS;
    const int bb  = rowbase >> 12;        // 128 | 4096: one batch per block
    const int tt0 = rowbase & (Tt - 1);

    // ---- init: r = latents (transposed into [k][row]), rr = ||r||^2 ----
    {
        const float* lb = latents + (size_t)bb * Cc * Tt + tt0 + un;
        float part = 0.f;
#pragma unroll
        for (int j = 0; j < KCH; ++j) {
            int k = ukg * KCH + j;
            float v = lb[(size_t)k * Tt];
            r_lds[k * ROWS + un] = v;
            part = fmaf(v, v, part);
        }
        rrp[ukg * ROWS + un] = part;
    }
    __syncthreads();
    if (t < ROWS)
        rr_lds[t] = (rrp[t] + rrp[ROWS + t]) + (rrp[2 * ROWS + t] + rrp[3 * ROWS + t]);
    __syncthreads();

    for (int q = 0; q < Qq; ++q) {
        const float* eq = emb + (size_t)q * Kk * Cc;

        f32x8 best_ = splat8(3.4e38f);
        i32x8 bk_   = {0, 0, 0, 0, 0, 0, 0, 0};
        f32x8 rr8   = *(const f32x8*)&rr_lds[ty * 8];

        // prologue: stage chunk 0 into buf 0
        {
            const float* src = eq + (size_t)cl * Cc + hk;
            f32x4 pf0 = *(const f32x4*)(src);
            f32x4 pf1 = *(const f32x4*)(src + 4);
            f32x4 pf2 = *(const f32x4*)(src + 8);
            f32x4 pf3 = *(const f32x4*)(src + 12);
#pragma unroll
            for (int i2 = 0; i2 < 4; ++i2) B_lds[(hk +      i2) * NTC + cl] = pf0[i2];
#pragma unroll
            for (int i2 = 0; i2 < 4; ++i2) B_lds[(hk +  4 + i2) * NTC + cl] = pf1[i2];
#pragma unroll
            for (int i2 = 0; i2 < 4; ++i2) B_lds[(hk +  8 + i2) * NTC + cl] = pf2[i2];
#pragma unroll
            for (int i2 = 0; i2 < 4; ++i2) B_lds[(hk + 12 + i2) * NTC + cl] = pf3[i2];
        }
        __syncthreads();

        f32x8 acc0, acc1, acc2, acc3, acc4, acc5, acc6, acc7;

        for (int id = 0; id < NCHUNK; ++id) {
            const int nt  = id >> 2;
            const int kc  = id & 3;
            const int cur = id & 1;
            if (kc == 0) {
                acc0 = splat8(0.f); acc1 = splat8(0.f); acc2 = splat8(0.f); acc3 = splat8(0.f);
                acc4 = splat8(0.f); acc5 = splat8(0.f); acc6 = splat8(0.f); acc7 = splat8(0.f);
            }

            // async-stage split: issue next chunk's global loads now...
            f32x4 pf0, pf1, pf2, pf3;
            if (id < NCHUNK - 1) {
                const int nid = id + 1;
                const float* src = eq + (size_t)(((nid >> 2) * NTC) + cl) * Cc
                                 + (nid & 3) * KCH + hk;
                pf0 = *(const f32x4*)(src);
                pf1 = *(const f32x4*)(src + 4);
                pf2 = *(const f32x4*)(src + 8);
                pf3 = *(const f32x4*)(src + 12);
            }

            // ...compute current chunk (latency hides under 2048 FMAs)...
            const float* Bb = B_lds + cur * (KCH * NTC);
#pragma unroll 8
            for (int kk = 0; kk < KCH; ++kk) {
                f32x8 a_  = *(const f32x8*)&r_lds[(kc * KCH + kk) * ROWS + ty * 8];
                f32x4 blo = *(const f32x4*)&Bb[kk * NTC + tx * 4];
                f32x4 bhi = *(const f32x4*)&Bb[kk * NTC + 128 + tx * 4];
                f32x8 b_  = __builtin_shufflevector(blo, bhi, 0, 1, 2, 3, 4, 5, 6, 7);
                acc0 = __builtin_elementwise_fma(splat8(a_[0]), b_, acc0);
                acc1 = __builtin_elementwise_fma(splat8(a_[1]), b_, acc1);
                acc2 = __builtin_elementwise_fma(splat8(a_[2]), b_, acc2);
                acc3 = __builtin_elementwise_fma(splat8(a_[3]), b_, acc3);
                acc4 = __builtin_elementwise_fma(splat8(a_[4]), b_, acc4);
                acc5 = __builtin_elementwise_fma(splat8(a_[5]), b_, acc5);
                acc6 = __builtin_elementwise_fma(splat8(a_[6]), b_, acc6);
                acc7 = __builtin_elementwise_fma(splat8(a_[7]), b_, acc7);
            }

            // ...then write staged data into the other buffer
            if (id < NCHUNK - 1) {
                float* Bn = B_lds + (cur ^ 1) * (KCH * NTC);
#pragma unroll
                for (int i2 = 0; i2 < 4; ++i2) Bn[(hk +      i2) * NTC + cl] = pf0[i2];
#pragma unroll
                for (int i2 = 0; i2 < 4; ++i2) Bn[(hk +  4 + i2) * NTC + cl] = pf1[i2];
#pragma unroll
                for (int i2 = 0; i2 < 4; ++i2) Bn[(hk +  8 + i2) * NTC + cl] = pf2[i2];
#pragma unroll
                for (int i2 = 0; i2 < 4; ++i2) Bn[(hk + 12 + i2) * NTC + cl] = pf3[i2];
            }
            __syncthreads();

            if (kc == 3) {
                // fold tile nt: d = (rr - 2*dot) + ee   (reference association)
                const int kb = nt * NTC + tx * 4;
                f32x4 eelo = *(const f32x4*)(ee + q * Kk + kb);
                f32x4 eehi = *(const f32x4*)(ee + q * Kk + kb + 128);
                f32x8 ee_  = __builtin_shufflevector(eelo, eehi, 0, 1, 2, 3, 4, 5, 6, 7);
#define FOLD_ROW(I_) {                                                        \
                f32x8 dv = __builtin_elementwise_fma(splat8(-2.0f), acc##I_,  \
                                                     splat8(rr8[I_])) + ee_;  \
                _Pragma("unroll")                                             \
                for (int c = 0; c < 8; ++c) {                                 \
                    float d = dv[c];                                          \
                    int code = kb + (c < 4 ? c : c + 124);                    \
                    bool lt = d < best_[I_];                                  \
                    best_[I_] = lt ? d : best_[I_];                           \
                    bk_[I_]   = lt ? code : bk_[I_];                          \
                } }
                FOLD_ROW(0) FOLD_ROW(1) FOLD_ROW(2) FOLD_ROW(3)
                FOLD_ROW(4) FOLD_ROW(5) FOLD_ROW(6) FOLD_ROW(7)
#undef FOLD_ROW
            }
        } // chunks

        // cross-tx reduce (32 lanes per row-group); (d,k) lexicographic
#pragma unroll
        for (int m = 1; m < 32; m <<= 1) {
#pragma unroll
            for (int i = 0; i < 8; ++i) {
                float od = __shfl_xor(best_[i], m);
                int   ok = __shfl_xor(bk_[i], m);
                bool rep = (od < best_[i]) || (od == best_[i] && ok < bk_[i]);
                best_[i] = rep ? od : best_[i];
                bk_[i]   = rep ? ok : bk_[i];
            }
        }
        if (tx == 0) {
#pragma unroll
            for (int i = 0; i < 8; ++i) {
                int row = ty * 8 + i;
                win[row] = bk_[i];
                codes[((size_t)bb * Qq + q) * Tt + tt0 + row] = (float)bk_[i];
            }
        }
        __syncthreads();

        // update: r -= e[win]; recompute rr
        {
            const float* er = eq + (size_t)win[un] * Cc + ukg * KCH;
            float part = 0.f;
#pragma unroll
            for (int j = 0; j < 8; ++j) {
                f32x4 ev = *(const f32x4*)(er + j * 4);
#pragma unroll
                for (int i2 = 0; i2 < 4; ++i2) {
                    int k = ukg * KCH + j * 4 + i2;
                    float rv = r_lds[k * ROWS + un] - ev[i2];
                    r_lds[k * ROWS + un] = rv;
                    part = fmaf(rv, rv, part);
                }
            }
            rrp[ukg * ROWS + un] = part;
        }
        __syncthreads();
        if (t < ROWS)
            rr_lds[t] = (rrp[t] + rrp[ROWS + t]) + (rrp[2 * ROWS + t] + rrp[3 * ROWS + t]);
        __syncthreads();
        // closs: sum of new rr over the block's rows
        if (t < 64) {
            double s = (double)rr_lds[t] + (double)rr_lds[t + 64];
#pragma unroll
            for (int off = 32; off; off >>= 1)
                s += __shfl_down(s, off);
            if (t == 0) atomicAdd(closs, s);
        }
    } // q

    // epilogue: quantized = latents - r_final
    {
        const float* lb = latents + (size_t)bb * Cc * Tt + tt0 + un;
        float* qb = quantized + (size_t)bb * Cc * Tt + tt0 + un;
#pragma unroll
        for (int j = 0; j < KCH; ++j) {
            int k = ukg * KCH + j;
            qb[(size_t)k * Tt] = lb[(size_t)k * Tt] - r_lds[k * ROWS + un];
        }
    }
}

__global__ void fin_kernel(const double* __restrict__ closs, float* __restrict__ loss_out) {
    loss_out[0] = (float)(*closs / (double)((size_t)Nn * Cc * Qq));
    loss_out[1] = 0.0f;
}

extern "C" void kernel_launch(void* const* d_in, const int* in_sizes, int n_in,
                              void* d_out, int out_size, void* d_ws, size_t ws_size,
                              hipStream_t stream) {
    const float* latents = (const float*)d_in[0];
    const float* emb     = (const float*)d_in[1];
    float* out       = (float*)d_out;
    float* quantized = out;                                   // B*C*T
    float* codes     = out + (size_t)Bq * Cc * Tt;            // B*Q*T
    float* loss      = codes + (size_t)Bq * Qq * Tt;          // 2 scalars
    double* closs    = (double*)d_ws;
    float*  ee       = (float*)((char*)d_ws + 64);

    const size_t smem = (size_t)(Cc * ROWS + 2 * KCH * NTC + 4 * ROWS + ROWS) * sizeof(float)
                      + ROWS * sizeof(int);   // 134144 B
    (void)hipFuncSetAttribute((const void*)vq_kernel,
                              hipFuncAttributeMaxDynamicSharedMemorySize, (int)smem);

    ee_kernel<<<(Qq * Kk + 255) / 256, 256, 0, stream>>>(emb, ee, closs);
    vq_kernel<<<Nn / ROWS, 512, smem, stream>>>(latents, emb, ee, quantized, codes, closs);
    fin_kernel<<<1, 1, 0, stream>>>(closs, loss);
}